// Round 17
// baseline (700.971 us; speedup 1.0000x reference)
//
#include <hip/hip_runtime.h>
#include <hip/hip_bf16.h>
#include <math.h>

#define D_MODEL 1024
#define N_LAYER 2
#define D_STATE 16
#define D_CONV  4
#define D_INNER 2048
#define DT_RANK 64
#define VOCAB   32000
#define BATCH   2
#define SEQLEN  1024
#define TOKENS  (BATCH*SEQLEN)   // 2048
#define NC      64               // scan chunks
#define CL      16               // steps per chunk (SEQLEN/NC)
#define XPZ     16               // x_proj split-K slices

typedef __hip_bfloat16 bf16;
typedef __bf16 bf16x8 __attribute__((ext_vector_type(8)));
typedef float f32x4 __attribute__((ext_vector_type(4)));

__device__ inline void gld_lds16(const bf16* g, bf16* l) {
    __builtin_amdgcn_global_load_lds(
        (const __attribute__((address_space(1))) void*)g,
        (__attribute__((address_space(3))) void*)l, 16, 0, 0);
}

__device__ inline float softplus_fast(float v) {
    return (v > 20.f) ? v : __logf(1.f + __expf(v));
}
__device__ inline float silu_fast(float v) {
    return v / (1.f + __expf(-v));
}
__device__ inline float bfu(unsigned short s) {
    unsigned u = ((unsigned)s) << 16;
    float f;
    __builtin_memcpy(&f, &u, 4);
    return f;
}
__device__ inline unsigned short bfb(float v) {
    bf16 b = __float2bfloat16(v);
    unsigned short s;
    __builtin_memcpy(&s, &b, 2);
    return s;
}

// ---------------- embedding gather + first rmsnorm (fused) ----------------
__global__ __launch_bounds__(256) void embed_rms(const int* __restrict__ x,
                                                 const float* __restrict__ emb,
                                                 const float* __restrict__ w,
                                                 float* __restrict__ h,
                                                 bf16* __restrict__ u) {
    int t = blockIdx.x;
    int tok = x[t];
    float4 v = ((const float4*)(emb + (size_t)tok * D_MODEL))[threadIdx.x];
    ((float4*)(h + (size_t)t * D_MODEL))[threadIdx.x] = v;
    float ss = v.x*v.x + v.y*v.y + v.z*v.z + v.w*v.w;
    #pragma unroll
    for (int off = 32; off > 0; off >>= 1) ss += __shfl_down(ss, off);
    __shared__ float red[4];
    int lane = threadIdx.x & 63, wid = threadIdx.x >> 6;
    if (lane == 0) red[wid] = ss;
    __syncthreads();
    float tot = red[0] + red[1] + red[2] + red[3];
    float scale = rsqrtf(tot * (1.0f / (float)D_MODEL) + 1e-5f);
    float4 wq = ((const float4*)w)[threadIdx.x];
    size_t o = (size_t)t * D_MODEL + threadIdx.x * 4;
    u[o+0] = __float2bfloat16(v.x * scale * wq.x);
    u[o+1] = __float2bfloat16(v.y * scale * wq.y);
    u[o+2] = __float2bfloat16(v.z * scale * wq.z);
    u[o+3] = __float2bfloat16(v.w * scale * wq.w);
}

// ---------------- f32 -> bf16 convert (n multiple of 4) ----------------
__global__ __launch_bounds__(256) void f32_to_bf16(const float* __restrict__ s,
                                                   bf16* __restrict__ d, int n) {
    int i = (blockIdx.x * 256 + threadIdx.x) * 4;
    if (i < n) {
        float4 v = *(const float4*)(s + i);
        d[i+0] = __float2bfloat16(v.x);
        d[i+1] = __float2bfloat16(v.y);
        d[i+2] = __float2bfloat16(v.z);
        d[i+3] = __float2bfloat16(v.w);
    }
}

// ---------------- x_proj weight: [96][2048] -> padded bf16 [128][2048] ----------------
__global__ __launch_bounds__(256) void conv_xproj_pad(const float* __restrict__ s,
                                                      bf16* __restrict__ d) {
    int col = blockIdx.x * 256 + threadIdx.x;
    int row = blockIdx.y;
    int layer = blockIdx.z;
    float v = (row < 96) ? s[((size_t)layer * 96 + row) * D_INNER + col] : 0.f;
    d[((size_t)layer * 128 + row) * D_INNER + col] = __float2bfloat16(v);
}

// ---------------- bf16 MFMA GEMM: C[M,N] (+)= A[M,K] * W[N,K]^T ----------------
// 128x128 tile, BK=64, double-buffered LDS, T2 XOR-swizzle, counted vmcnt(8).
// bfout!=0: C written as bf16 (no acc on that path). z: K-split slice.
__global__ __launch_bounds__(256) void gemm_bf16(
    const bf16* __restrict__ A, int lda,
    const bf16* __restrict__ W, int ldw,
    float* __restrict__ C, int ldc,
    int N, int K, int acc, int swz, int M, int bfout)
{
    __shared__ bf16 lds[2][2][128 * 64];
    int bx = blockIdx.x, by = blockIdx.y;
    if (swz) {
        int bid = by * gridDim.x + bx;
        int q = (gridDim.x * gridDim.y) >> 3;
        int n = (bid & 7) * q + (bid >> 3);
        by = n % gridDim.y;
        bx = n / gridDim.y;
    }
    const int z = blockIdx.z;
    A += (size_t)z * K;
    W += (size_t)z * K;
    float* Cf = C + (size_t)z * M * (size_t)ldc;
    bf16*  Cb = (bf16*)C + (size_t)z * M * (size_t)ldc;

    const int tid  = threadIdx.x;
    const int wave = tid >> 6;
    const int lane = tid & 63;
    const int wr = wave >> 1, wc = wave & 1;
    const size_t rowBase = (size_t)by * 128;
    const size_t colBase = (size_t)bx * 128;

    const int srow = 8 * wave + (lane >> 3);
    const int scol = ((lane & 7) ^ (lane >> 3)) << 3;
    const bf16* aGs = A + (rowBase + srow) * (size_t)lda + scol;
    const bf16* bGs = W + (colBase + srow) * (size_t)ldw + scol;

#define STAGE(tt, bb) do {                                                      \
        const size_t kofs_ = (size_t)(tt) * 64;                                 \
        _Pragma("unroll")                                                       \
        for (int i_ = 0; i_ < 4; ++i_) {                                        \
            gld_lds16(aGs + kofs_ + (size_t)(32 * i_) * lda,                    \
                      &lds[bb][0][(32 * i_ + 8 * wave) * 64]);                  \
            gld_lds16(bGs + kofs_ + (size_t)(32 * i_) * ldw,                    \
                      &lds[bb][1][(32 * i_ + 8 * wave) * 64]);                  \
        }                                                                       \
    } while (0)

    f32x4 accv[4][4];
    #pragma unroll
    for (int i = 0; i < 4; ++i)
        #pragma unroll
        for (int j = 0; j < 4; ++j)
            accv[i][j] = f32x4{0.f, 0.f, 0.f, 0.f};

    const int arow0 = wr * 64 + (lane & 15);
    const int brow0 = wc * 64 + (lane & 15);
    const int h8  = (lane >> 4) << 3;
    const int sw8 = (lane & 7) << 3;

    const int NT = K >> 6;
    STAGE(0, 0);
    for (int t = 0; t < NT; ++t) {
        const int cur = t & 1;
        if (t + 1 < NT) {
            STAGE(t + 1, cur ^ 1);
            asm volatile("s_waitcnt vmcnt(8)" ::: "memory");
        } else {
            asm volatile("s_waitcnt vmcnt(0)" ::: "memory");
        }
        __builtin_amdgcn_s_barrier();

        const bf16* Ab = &lds[cur][0][0];
        const bf16* Bb = &lds[cur][1][0];
        #pragma unroll
        for (int kk = 0; kk < 2; ++kk) {
            const int cs = ((kk << 5) + h8) ^ sw8;
            bf16x8 af[4], bv[4];
            #pragma unroll
            for (int i = 0; i < 4; ++i)
                af[i] = *(const bf16x8*)(Ab + (arow0 + 16 * i) * 64 + cs);
            #pragma unroll
            for (int j = 0; j < 4; ++j)
                bv[j] = *(const bf16x8*)(Bb + (brow0 + 16 * j) * 64 + cs);
            #pragma unroll
            for (int i = 0; i < 4; ++i)
                #pragma unroll
                for (int j = 0; j < 4; ++j)
                    accv[i][j] = __builtin_amdgcn_mfma_f32_16x16x32_bf16(
                        af[i], bv[j], accv[i][j], 0, 0, 0);
        }
        asm volatile("s_waitcnt lgkmcnt(0)" ::: "memory");
        __builtin_amdgcn_s_barrier();
    }
#undef STAGE

    const int cl = lane & 15;
    const int rg = (lane >> 4) * 4;
    #pragma unroll
    for (int i = 0; i < 4; ++i) {
        #pragma unroll
        for (int j = 0; j < 4; ++j) {
            int col = (int)colBase + wc * 64 + j * 16 + cl;
            if (col < N) {
                size_t base = (rowBase + wr * 64 + i * 16 + rg) * (size_t)ldc + col;
                if (bfout) {
                    #pragma unroll
                    for (int r = 0; r < 4; ++r)
                        Cb[base + (size_t)r * ldc] = __float2bfloat16(accv[i][j][r]);
                } else {
                    #pragma unroll
                    for (int r = 0; r < 4; ++r) {
                        size_t idx = base + (size_t)r * ldc;
                        Cf[idx] = acc ? Cf[idx] + accv[i][j][r] : accv[i][j][r];
                    }
                }
            }
        }
    }
}

// ---------------- wide GEMM (K=1024), 3-slot, 8 waves ----------
// 256x128 tile, BK=32, LDS 72KB (2 blocks/CU), one barrier/K-step, vmcnt(3).
__global__ __launch_bounds__(512) void gemm_wide3(
    const bf16* __restrict__ A,
    const bf16* __restrict__ W,
    float* __restrict__ C, int ldc, int bfout)
{
    __shared__ bf16 ldsA[3][256 * 32];   // 48 KB
    __shared__ bf16 ldsB[3][128 * 32];   // 24 KB
    int bx = blockIdx.x, by = blockIdx.y;
    {
        int bid = by * gridDim.x + bx;
        int n = (bid & 7) * ((gridDim.x * gridDim.y) >> 3) + (bid >> 3);
        by = n & 7;
        bx = n >> 3;
    }
    const int tid  = threadIdx.x;
    const int wave = tid >> 6;
    const int lane = tid & 63;
    const int wr = wave >> 1;
    const int wc = wave & 1;
    const size_t rowBase = (size_t)by * 256;
    const size_t colBase = (size_t)bx * 128;

    const int srow   = lane >> 2;
    const int schunk = ((lane & 3) ^ ((lane >> 3) & 3)) << 3;
    const bf16* aG0 = A + (rowBase + 16 * wave       + srow) * (size_t)D_MODEL + schunk;
    const bf16* aG1 = A + (rowBase + 128 + 16 * wave + srow) * (size_t)D_MODEL + schunk;
    const bf16* bG  = W + (colBase + 16 * wave       + srow) * (size_t)D_MODEL + schunk;

#define STAGEW(tt, sAp, sBp) do {                                               \
        const size_t ko_ = (size_t)(tt) * 32;                                   \
        gld_lds16(aG0 + ko_, (sAp) + 512 * wave);                               \
        gld_lds16(aG1 + ko_, (sAp) + 512 * (8 + wave));                         \
        gld_lds16(bG  + ko_, (sBp) + 512 * wave);                               \
    } while (0)

    f32x4 accv[4][4];
    #pragma unroll
    for (int i = 0; i < 4; ++i)
        #pragma unroll
        for (int j = 0; j < 4; ++j)
            accv[i][j] = f32x4{0.f, 0.f, 0.f, 0.f};

    const int l15 = lane & 15;
    const int cs = (((lane >> 4) ^ ((l15 >> 1) & 3)) << 3);
    const int arow0 = wr * 64 + l15;
    const int brow0 = wc * 64 + l15;

    STAGEW(0, &ldsA[0][0], &ldsB[0][0]);
    STAGEW(1, &ldsA[1][0], &ldsB[1][0]);

    int rs = 0, ps = 2;
    #pragma unroll 1
    for (int t = 0; t < 32; ++t) {
        if (t < 31) { asm volatile("s_waitcnt vmcnt(3)" ::: "memory"); }
        else        { asm volatile("s_waitcnt vmcnt(0)" ::: "memory"); }
        __builtin_amdgcn_s_barrier();
        __builtin_amdgcn_sched_barrier(0);

        if (t + 2 < 32) STAGEW(t + 2, &ldsA[ps][0], &ldsB[ps][0]);

        const bf16* Ab = &ldsA[rs][0];
        const bf16* Bb = &ldsB[rs][0];
        bf16x8 af[4], bv[4];
        #pragma unroll
        for (int i = 0; i < 4; ++i)
            af[i] = *(const bf16x8*)(Ab + (arow0 + 16 * i) * 32 + cs);
        #pragma unroll
        for (int j = 0; j < 4; ++j)
            bv[j] = *(const bf16x8*)(Bb + (brow0 + 16 * j) * 32 + cs);
        #pragma unroll
        for (int i = 0; i < 4; ++i)
            #pragma unroll
            for (int j = 0; j < 4; ++j)
                accv[i][j] = __builtin_amdgcn_mfma_f32_16x16x32_bf16(
                    af[i], bv[j], accv[i][j], 0, 0, 0);

        rs = (rs == 2) ? 0 : rs + 1;
        ps = (ps == 2) ? 0 : ps + 1;
    }
#undef STAGEW

    const int cl = l15;
    const int rg = (lane >> 4) * 4;
    #pragma unroll
    for (int i = 0; i < 4; ++i) {
        #pragma unroll
        for (int j = 0; j < 4; ++j) {
            int col = (int)colBase + wc * 64 + j * 16 + cl;
            size_t base = (rowBase + wr * 64 + i * 16 + rg) * (size_t)ldc + col;
            if (bfout) {
                bf16* Cb = (bf16*)C;
                #pragma unroll
                for (int r = 0; r < 4; ++r)
                    Cb[base + (size_t)r * ldc] = __float2bfloat16(accv[i][j][r]);
            } else {
                #pragma unroll
                for (int r = 0; r < 4; ++r)
                    C[base + (size_t)r * ldc] = accv[i][j][r];
            }
        }
    }
}

// ---------------- causal depthwise conv (k=4) + bias + silu, 2 d x 8 l per thread ----
__global__ __launch_bounds__(256) void conv_silu_kernel(const bf16* __restrict__ xz,
                                                        const float* __restrict__ cw,
                                                        const float* __restrict__ cb,
                                                        bf16* __restrict__ xcb) {
    int d  = (blockIdx.x * 256 + threadIdx.x) * 2;
    int l0 = blockIdx.y * 8;
    int b  = blockIdx.z;
    float4 wa = *(const float4*)(cw + d * 4);
    float4 wb = *(const float4*)(cw + d * 4 + 4);
    float2 bias = *(const float2*)(cb + d);
    const bf16* base = xz + (size_t)b * SEQLEN * (2 * D_INNER) + d;

    float a0 = 0.f, a1 = 0.f, a2 = 0.f;
    float b0 = 0.f, b1 = 0.f, b2 = 0.f;
    #pragma unroll
    for (int j = 0; j < 3; ++j) {
        int l = l0 - 3 + j;
        float va = 0.f, vb = 0.f;
        if (l >= 0) {
            unsigned v;
            __builtin_memcpy(&v, base + (size_t)l * (2 * D_INNER), 4);
            va = bfu((unsigned short)v);
            vb = bfu((unsigned short)(v >> 16));
        }
        if (j == 0) { a0 = va; b0 = vb; }
        else if (j == 1) { a1 = va; b1 = vb; }
        else { a2 = va; b2 = vb; }
    }
    #pragma unroll
    for (int i = 0; i < 8; ++i) {
        unsigned v;
        __builtin_memcpy(&v, base + (size_t)(l0 + i) * (2 * D_INNER), 4);
        float ca = bfu((unsigned short)v);
        float cbv = bfu((unsigned short)(v >> 16));
        float sa = silu_fast(bias.x + wa.x * a0 + wa.y * a1 + wa.z * a2 + wa.w * ca);
        float sb = silu_fast(bias.y + wb.x * b0 + wb.y * b1 + wb.z * b2 + wb.w * cbv);
        unsigned o = (unsigned)bfb(sa) | ((unsigned)bfb(sb) << 16);
        unsigned* dst = (unsigned*)(xcb + ((size_t)b * SEQLEN + l0 + i) * D_INNER + d);
        *dst = o;
        a0 = a1; a1 = a2; a2 = ca;
        b0 = b1; b1 = b2; b2 = cbv;
    }
}

// ---------------- x_proj split-K reduce: sum 16 bf16 partials -> bf16 ----------------
__global__ __launch_bounds__(256) void reduce_xproj(const bf16* __restrict__ px,
                                                    bf16* __restrict__ dbl_b) {
    int i = blockIdx.x * 256 + threadIdx.x;
    float s = 0.f;
    #pragma unroll
    for (int z = 0; z < XPZ; ++z) {
        unsigned short v;
        __builtin_memcpy(&v, px + (size_t)z * (TOKENS * 96) + i, 2);
        s += bfu(v);
    }
    dbl_b[i] = __float2bfloat16(s);
}

// ---------------- out_proj reduce (bf16 partials) + residual + rmsnorm -> u_b ----
__global__ __launch_bounds__(256) void reduce_oproj_rms(const bf16* __restrict__ po,
                                                        float* __restrict__ h,
                                                        const float* __restrict__ w,
                                                        bf16* __restrict__ u) {
    int t = blockIdx.x;
    size_t base = (size_t)t * D_MODEL + threadIdx.x * 4;
    ushort4 ua = *(const ushort4*)(po + base);
    ushort4 ub = *(const ushort4*)(po + (size_t)TOKENS * D_MODEL + base);
    float4 hv = *(const float4*)(h + base);
    hv.x += bfu(ua.x) + bfu(ub.x);
    hv.y += bfu(ua.y) + bfu(ub.y);
    hv.z += bfu(ua.z) + bfu(ub.z);
    hv.w += bfu(ua.w) + bfu(ub.w);
    *(float4*)(h + base) = hv;
    float ss = hv.x*hv.x + hv.y*hv.y + hv.z*hv.z + hv.w*hv.w;
    #pragma unroll
    for (int off = 32; off > 0; off >>= 1) ss += __shfl_down(ss, off);
    __shared__ float red[4];
    int lane = threadIdx.x & 63, wid = threadIdx.x >> 6;
    if (lane == 0) red[wid] = ss;
    __syncthreads();
    float tot = red[0] + red[1] + red[2] + red[3];
    float scale = rsqrtf(tot * (1.0f / (float)D_MODEL) + 1e-5f);
    float4 wq = ((const float4*)w)[threadIdx.x];
    u[base+0] = __float2bfloat16(hv.x * scale * wq.x);
    u[base+1] = __float2bfloat16(hv.y * scale * wq.y);
    u[base+2] = __float2bfloat16(hv.z * scale * wq.z);
    u[base+3] = __float2bfloat16(hv.w * scale * wq.w);
}

// ---------------- fused 3-phase scan: one block = 4 channels x 64 chunks --------
// Phase A: per-thread chunk summary (regs). Kogge-Stone inclusive scan over
// chunks in LDS (6 steps) -> true init states in f32 regs (no global scratch,
// no bf16 round-trip). Phase C: same-thread replay (L1-hot) + gated emit.
__global__ __launch_bounds__(256) void scan_fused(const bf16* __restrict__ dtp,
                                                  const float* __restrict__ dt_bias,
                                                  const bf16* __restrict__ dbl,
                                                  const bf16* __restrict__ xc,
                                                  const bf16* __restrict__ xz,
                                                  const float* __restrict__ A_log,
                                                  const float* __restrict__ Dp,
                                                  bf16* __restrict__ y) {
    const int d_sub = threadIdx.x >> 6;      // 0..3
    const int c     = threadIdx.x & 63;      // chunk 0..63
    const int d     = blockIdx.x * 4 + d_sub;
    const int b     = blockIdx.y;

    float A[D_STATE];
    #pragma unroll
    for (int n = 0; n < D_STATE; ++n) A[n] = -__expf(A_log[d * D_STATE + n]);
    const float bias = dt_bias[d];

    const size_t t0 = (size_t)b * SEQLEN + c * CL;
    const bf16* drow = dbl + t0 * 96 + DT_RANK;

    // ---- phase A: chunk summary from zero init ----
    float st[D_STATE];
    #pragma unroll
    for (int n = 0; n < D_STATE; ++n) st[n] = 0.f;
    float dts = 0.f;
    for (int l = 0; l < CL; ++l) {
        float dtv = softplus_fast(__bfloat162float(dtp[(t0 + l) * D_INNER + d]) + bias);
        dts += dtv;
        float dx = dtv * __bfloat162float(xc[(t0 + l) * D_INNER + d]);
        bf16x8 B0 = *(const bf16x8*)(drow + l * 96);
        bf16x8 B1 = *(const bf16x8*)(drow + l * 96 + 8);
        #pragma unroll
        for (int n = 0; n < D_STATE; ++n) {
            float a = __expf(dtv * A[n]);
            float Bv = (n < 8) ? (float)B0[n] : (float)B1[n - 8];
            st[n] = a * st[n] + dx * Bv;
        }
    }
    float ap[D_STATE];
    #pragma unroll
    for (int n = 0; n < D_STATE; ++n) ap[n] = __expf(dts * A[n]);

    // ---- block-local inclusive scan over chunks (payload: ap, st) ----
    __shared__ float sA_[4][64][D_STATE];
    __shared__ float sS_[4][64][D_STATE];
    #pragma unroll 1
    for (int off = 1; off < 64; off <<= 1) {
        #pragma unroll
        for (int n = 0; n < D_STATE; ++n) {
            sA_[d_sub][c][n] = ap[n];
            sS_[d_sub][c][n] = st[n];
        }
        __syncthreads();
        if (c >= off) {
            #pragma unroll
            for (int n = 0; n < D_STATE; ++n) {
                float pa = sA_[d_sub][c - off][n];
                float ps = sS_[d_sub][c - off][n];
                st[n] = ap[n] * ps + st[n];
                ap[n] = ap[n] * pa;
            }
        }
        __syncthreads();
    }
    // exclusive: init for chunk c = inclusive state of chunk c-1
    #pragma unroll
    for (int n = 0; n < D_STATE; ++n) sS_[d_sub][c][n] = st[n];
    __syncthreads();
    #pragma unroll
    for (int n = 0; n < D_STATE; ++n)
        st[n] = (c == 0) ? 0.f : sS_[d_sub][c - 1][n];

    // ---- phase C: replay with true init, emit gated y ----
    const float Dv = Dp[d];
    for (int l = 0; l < CL; ++l) {
        float dtv = softplus_fast(__bfloat162float(dtp[(t0 + l) * D_INNER + d]) + bias);
        float xcv = __bfloat162float(xc[(t0 + l) * D_INNER + d]);
        float dx = dtv * xcv;
        bf16x8 B0 = *(const bf16x8*)(drow + l * 96);
        bf16x8 B1 = *(const bf16x8*)(drow + l * 96 + 8);
        bf16x8 C0 = *(const bf16x8*)(drow + l * 96 + 16);
        bf16x8 C1 = *(const bf16x8*)(drow + l * 96 + 24);
        float acc = 0.f;
        #pragma unroll
        for (int n = 0; n < D_STATE; ++n) {
            float a = __expf(dtv * A[n]);
            float Bv = (n < 8) ? (float)B0[n] : (float)B1[n - 8];
            float Cv = (n < 8) ? (float)C0[n] : (float)C1[n - 8];
            st[n] = a * st[n] + dx * Bv;
            acc += st[n] * Cv;
        }
        acc += xcv * Dv;
        float zv = __bfloat162float(xz[(t0 + l) * (2 * D_INNER) + D_INNER + d]);
        y[(t0 + l) * D_INNER + d] = __float2bfloat16(acc * silu_fast(zv));
    }
}

extern "C" void kernel_launch(void* const* d_in, const int* in_sizes, int n_in,
                              void* d_out, int out_size, void* d_ws, size_t ws_size,
                              hipStream_t stream) {
    const int*   x          = (const int*)  d_in[0];
    const float* emb        = (const float*)d_in[1];
    const float* norm_w     = (const float*)d_in[2];
    const float* in_proj_w  = (const float*)d_in[3];
    const float* conv_w     = (const float*)d_in[4];
    const float* conv_b     = (const float*)d_in[5];
    const float* x_proj_w   = (const float*)d_in[6];
    const float* dt_proj_w  = (const float*)d_in[7];
    const float* dt_bias    = (const float*)d_in[8];
    const float* A_log      = (const float*)d_in[9];
    const float* Dp         = (const float*)d_in[10];
    const float* out_proj_w = (const float*)d_in[11];
    const float* fnorm_w    = (const float*)d_in[12];
    float* out = (float*)d_out;
    float* ws  = (float*)d_ws;

    // ---- ws scratch layout (float offsets) ----
    bf16*  embf   = (bf16*)ws;              // [32000][1024] bf16
    bf16*  u_b    = (bf16*)(ws + 16384000); // [2048][1024] bf16
    bf16*  xz_b   = (bf16*)(ws + 17432576); // [2048][4096] bf16
    bf16*  dtp_b  = (bf16*)(ws + 25821184); // [2048][2048] bf16
    bf16*  xc_b   = (bf16*)(ws + 30015488); // [2048][2048] bf16
    float* h      = ws + 36306944;          // [2048][1024]
    bf16*  dbl_b  = (bf16*)(ws + 38600704); // [2048][96] bf16
    bf16*  y_b    = (bf16*)(ws + 38699008); // [2048][2048] bf16
    bf16*  inpj_b = (bf16*)(ws + 40796160); // [2][4096][1024] bf16
    bf16*  xpj_b  = (bf16*)(ws + 44990464); // [2][128][2048] bf16
    bf16*  dtpj_b = (bf16*)(ws + 45252608); // [2][2048][64] bf16
    bf16*  otpj_b = (bf16*)(ws + 45383680); // [2][1024][2048] bf16
    bf16*  px_b   = (bf16*)(ws + 53772288); // [16][2048][96] bf16
    bf16*  po_b   = (bf16*)(ws + 56918016); // [2][2048][1024] bf16

    f32_to_bf16<<<(VOCAB*D_MODEL/4 + 255)/256, 256, 0, stream>>>(emb, embf, VOCAB*D_MODEL);
    f32_to_bf16<<<(2*2*D_INNER*D_MODEL/4 + 255)/256, 256, 0, stream>>>(in_proj_w,  inpj_b, 2*2*D_INNER*D_MODEL);
    conv_xproj_pad<<<dim3(D_INNER/256, 128, N_LAYER), 256, 0, stream>>>(x_proj_w, xpj_b);
    f32_to_bf16<<<(2*D_INNER*DT_RANK/4 + 255)/256, 256, 0, stream>>>(dt_proj_w,  dtpj_b, 2*D_INNER*DT_RANK);
    f32_to_bf16<<<(2*D_MODEL*D_INNER/4 + 255)/256, 256, 0, stream>>>(out_proj_w, otpj_b, 2*D_MODEL*D_INNER);

    embed_rms<<<TOKENS, 256, 0, stream>>>(x, emb, norm_w, h, u_b);

    for (int layer = 0; layer < N_LAYER; ++layer) {
        gemm_wide3<<<dim3(4096/128, TOKENS/256), 512, 0, stream>>>(
            u_b, inpj_b + (size_t)layer * 2 * D_INNER * D_MODEL,
            (float*)xz_b, 2 * D_INNER, 1);
        conv_silu_kernel<<<dim3(D_INNER/512, SEQLEN/8, BATCH), 256, 0, stream>>>(
            xz_b, conv_w + (size_t)layer * D_INNER * D_CONV, conv_b + layer * D_INNER,
            xc_b);
        gemm_bf16<<<dim3(1, TOKENS/128, XPZ), 256, 0, stream>>>(
            xc_b, D_INNER, xpj_b + (size_t)layer * 128 * D_INNER, D_INNER,
            (float*)px_b, 96, 96, 128, 0, 0, TOKENS, 1);
        reduce_xproj<<<(TOKENS*96)/256, 256, 0, stream>>>(px_b, dbl_b);
        gemm_bf16<<<dim3(D_INNER/128, TOKENS/128), 256, 0, stream>>>(
            dbl_b, 96, dtpj_b + (size_t)layer * D_INNER * DT_RANK, DT_RANK,
            (float*)dtp_b, D_INNER, D_INNER, DT_RANK, 0, 1, TOKENS, 1);
        scan_fused<<<dim3(D_INNER/4, BATCH), 256, 0, stream>>>(
            dtp_b, dt_bias + layer * D_INNER, dbl_b, xc_b, xz_b,
            A_log + (size_t)layer * D_INNER * D_STATE, Dp + layer * D_INNER, y_b);
        gemm_bf16<<<dim3(D_MODEL/128, TOKENS/128, 2), 256, 0, stream>>>(
            y_b, D_INNER, otpj_b + (size_t)layer * D_MODEL * D_INNER, D_INNER,
            (float*)po_b, D_MODEL, D_MODEL, 1024, 0, 1, TOKENS, 1);
        reduce_oproj_rms<<<TOKENS, 256, 0, stream>>>(
            po_b, h, (layer + 1 < N_LAYER) ? (norm_w + (layer + 1) * D_MODEL) : fnorm_w,
            u_b);
    }

    // vocab GEMM: proven 8-wave 3-slot kernel, 250x8 grid, f32 out
    gemm_wide3<<<dim3(VOCAB/128, TOKENS/256), 512, 0, stream>>>(u_b, embf, out, VOCAB, 0);
}

// Round 18
// 505.383 us; speedup vs baseline: 1.3870x; 1.3870x over previous
//
#include <hip/hip_runtime.h>
#include <hip/hip_bf16.h>
#include <math.h>

#define D_MODEL 1024
#define N_LAYER 2
#define D_STATE 16
#define D_CONV  4
#define D_INNER 2048
#define DT_RANK 64
#define VOCAB   32000
#define BATCH   2
#define SEQLEN  1024
#define TOKENS  (BATCH*SEQLEN)   // 2048
#define NC      64               // scan chunks
#define CL      16               // steps per chunk (SEQLEN/NC)
#define XPZ     16               // x_proj split-K slices

typedef __hip_bfloat16 bf16;
typedef __bf16 bf16x8 __attribute__((ext_vector_type(8)));
typedef float f32x4 __attribute__((ext_vector_type(4)));

__device__ inline void gld_lds16(const bf16* g, bf16* l) {
    __builtin_amdgcn_global_load_lds(
        (const __attribute__((address_space(1))) void*)g,
        (__attribute__((address_space(3))) void*)l, 16, 0, 0);
}

__device__ inline float softplus_fast(float v) {
    return (v > 20.f) ? v : __logf(1.f + __expf(v));
}
__device__ inline float silu_fast(float v) {
    return v / (1.f + __expf(-v));
}
__device__ inline float bfu(unsigned short s) {
    unsigned u = ((unsigned)s) << 16;
    float f;
    __builtin_memcpy(&f, &u, 4);
    return f;
}
__device__ inline unsigned short bfb(float v) {
    bf16 b = __float2bfloat16(v);
    unsigned short s;
    __builtin_memcpy(&s, &b, 2);
    return s;
}

// ---------------- embedding gather + first rmsnorm (fused) ----------------
__global__ __launch_bounds__(256) void embed_rms(const int* __restrict__ x,
                                                 const float* __restrict__ emb,
                                                 const float* __restrict__ w,
                                                 float* __restrict__ h,
                                                 bf16* __restrict__ u) {
    int t = blockIdx.x;
    int tok = x[t];
    float4 v = ((const float4*)(emb + (size_t)tok * D_MODEL))[threadIdx.x];
    ((float4*)(h + (size_t)t * D_MODEL))[threadIdx.x] = v;
    float ss = v.x*v.x + v.y*v.y + v.z*v.z + v.w*v.w;
    #pragma unroll
    for (int off = 32; off > 0; off >>= 1) ss += __shfl_down(ss, off);
    __shared__ float red[4];
    int lane = threadIdx.x & 63, wid = threadIdx.x >> 6;
    if (lane == 0) red[wid] = ss;
    __syncthreads();
    float tot = red[0] + red[1] + red[2] + red[3];
    float scale = rsqrtf(tot * (1.0f / (float)D_MODEL) + 1e-5f);
    float4 wq = ((const float4*)w)[threadIdx.x];
    size_t o = (size_t)t * D_MODEL + threadIdx.x * 4;
    u[o+0] = __float2bfloat16(v.x * scale * wq.x);
    u[o+1] = __float2bfloat16(v.y * scale * wq.y);
    u[o+2] = __float2bfloat16(v.z * scale * wq.z);
    u[o+3] = __float2bfloat16(v.w * scale * wq.w);
}

// ---------------- f32 -> bf16 convert (n multiple of 4) ----------------
__global__ __launch_bounds__(256) void f32_to_bf16(const float* __restrict__ s,
                                                   bf16* __restrict__ d, int n) {
    int i = (blockIdx.x * 256 + threadIdx.x) * 4;
    if (i < n) {
        float4 v = *(const float4*)(s + i);
        d[i+0] = __float2bfloat16(v.x);
        d[i+1] = __float2bfloat16(v.y);
        d[i+2] = __float2bfloat16(v.z);
        d[i+3] = __float2bfloat16(v.w);
    }
}

// ---------------- x_proj weight: [96][2048] -> padded bf16 [128][2048] ----------------
__global__ __launch_bounds__(256) void conv_xproj_pad(const float* __restrict__ s,
                                                      bf16* __restrict__ d) {
    int col = blockIdx.x * 256 + threadIdx.x;
    int row = blockIdx.y;
    int layer = blockIdx.z;
    float v = (row < 96) ? s[((size_t)layer * 96 + row) * D_INNER + col] : 0.f;
    d[((size_t)layer * 128 + row) * D_INNER + col] = __float2bfloat16(v);
}

// ---------------- bf16 MFMA GEMM: C[M,N] (+)= A[M,K] * W[N,K]^T ----------------
// 128x128 tile, BK=64, double-buffered LDS, T2 XOR-swizzle, counted vmcnt(8).
// bfout!=0: C written as bf16 (no acc on that path). z: K-split slice.
__global__ __launch_bounds__(256) void gemm_bf16(
    const bf16* __restrict__ A, int lda,
    const bf16* __restrict__ W, int ldw,
    float* __restrict__ C, int ldc,
    int N, int K, int acc, int swz, int M, int bfout)
{
    __shared__ bf16 lds[2][2][128 * 64];
    int bx = blockIdx.x, by = blockIdx.y;
    if (swz) {
        int bid = by * gridDim.x + bx;
        int q = (gridDim.x * gridDim.y) >> 3;
        int n = (bid & 7) * q + (bid >> 3);
        by = n % gridDim.y;
        bx = n / gridDim.y;
    }
    const int z = blockIdx.z;
    A += (size_t)z * K;
    W += (size_t)z * K;
    float* Cf = C + (size_t)z * M * (size_t)ldc;
    bf16*  Cb = (bf16*)C + (size_t)z * M * (size_t)ldc;

    const int tid  = threadIdx.x;
    const int wave = tid >> 6;
    const int lane = tid & 63;
    const int wr = wave >> 1, wc = wave & 1;
    const size_t rowBase = (size_t)by * 128;
    const size_t colBase = (size_t)bx * 128;

    const int srow = 8 * wave + (lane >> 3);
    const int scol = ((lane & 7) ^ (lane >> 3)) << 3;
    const bf16* aGs = A + (rowBase + srow) * (size_t)lda + scol;
    const bf16* bGs = W + (colBase + srow) * (size_t)ldw + scol;

#define STAGE(tt, bb) do {                                                      \
        const size_t kofs_ = (size_t)(tt) * 64;                                 \
        _Pragma("unroll")                                                       \
        for (int i_ = 0; i_ < 4; ++i_) {                                        \
            gld_lds16(aGs + kofs_ + (size_t)(32 * i_) * lda,                    \
                      &lds[bb][0][(32 * i_ + 8 * wave) * 64]);                  \
            gld_lds16(bGs + kofs_ + (size_t)(32 * i_) * ldw,                    \
                      &lds[bb][1][(32 * i_ + 8 * wave) * 64]);                  \
        }                                                                       \
    } while (0)

    f32x4 accv[4][4];
    #pragma unroll
    for (int i = 0; i < 4; ++i)
        #pragma unroll
        for (int j = 0; j < 4; ++j)
            accv[i][j] = f32x4{0.f, 0.f, 0.f, 0.f};

    const int arow0 = wr * 64 + (lane & 15);
    const int brow0 = wc * 64 + (lane & 15);
    const int h8  = (lane >> 4) << 3;
    const int sw8 = (lane & 7) << 3;

    const int NT = K >> 6;
    STAGE(0, 0);
    for (int t = 0; t < NT; ++t) {
        const int cur = t & 1;
        if (t + 1 < NT) {
            STAGE(t + 1, cur ^ 1);
            asm volatile("s_waitcnt vmcnt(8)" ::: "memory");
        } else {
            asm volatile("s_waitcnt vmcnt(0)" ::: "memory");
        }
        __builtin_amdgcn_s_barrier();

        const bf16* Ab = &lds[cur][0][0];
        const bf16* Bb = &lds[cur][1][0];
        #pragma unroll
        for (int kk = 0; kk < 2; ++kk) {
            const int cs = ((kk << 5) + h8) ^ sw8;
            bf16x8 af[4], bv[4];
            #pragma unroll
            for (int i = 0; i < 4; ++i)
                af[i] = *(const bf16x8*)(Ab + (arow0 + 16 * i) * 64 + cs);
            #pragma unroll
            for (int j = 0; j < 4; ++j)
                bv[j] = *(const bf16x8*)(Bb + (brow0 + 16 * j) * 64 + cs);
            #pragma unroll
            for (int i = 0; i < 4; ++i)
                #pragma unroll
                for (int j = 0; j < 4; ++j)
                    accv[i][j] = __builtin_amdgcn_mfma_f32_16x16x32_bf16(
                        af[i], bv[j], accv[i][j], 0, 0, 0);
        }
        asm volatile("s_waitcnt lgkmcnt(0)" ::: "memory");
        __builtin_amdgcn_s_barrier();
    }
#undef STAGE

    const int cl = lane & 15;
    const int rg = (lane >> 4) * 4;
    #pragma unroll
    for (int i = 0; i < 4; ++i) {
        #pragma unroll
        for (int j = 0; j < 4; ++j) {
            int col = (int)colBase + wc * 64 + j * 16 + cl;
            if (col < N) {
                size_t base = (rowBase + wr * 64 + i * 16 + rg) * (size_t)ldc + col;
                if (bfout) {
                    #pragma unroll
                    for (int r = 0; r < 4; ++r)
                        Cb[base + (size_t)r * ldc] = __float2bfloat16(accv[i][j][r]);
                } else {
                    #pragma unroll
                    for (int r = 0; r < 4; ++r) {
                        size_t idx = base + (size_t)r * ldc;
                        Cf[idx] = acc ? Cf[idx] + accv[i][j][r] : accv[i][j][r];
                    }
                }
            }
        }
    }
}

// ---------------- wide GEMM (K=1024), 3-slot, 8 waves ----------
// 256x128 tile, BK=32, LDS 72KB (2 blocks/CU), one barrier/K-step, vmcnt(3).
__global__ __launch_bounds__(512) void gemm_wide3(
    const bf16* __restrict__ A,
    const bf16* __restrict__ W,
    float* __restrict__ C, int ldc, int bfout)
{
    __shared__ bf16 ldsA[3][256 * 32];   // 48 KB
    __shared__ bf16 ldsB[3][128 * 32];   // 24 KB
    int bx = blockIdx.x, by = blockIdx.y;
    {
        int bid = by * gridDim.x + bx;
        int n = (bid & 7) * ((gridDim.x * gridDim.y) >> 3) + (bid >> 3);
        by = n & 7;
        bx = n >> 3;
    }
    const int tid  = threadIdx.x;
    const int wave = tid >> 6;
    const int lane = tid & 63;
    const int wr = wave >> 1;
    const int wc = wave & 1;
    const size_t rowBase = (size_t)by * 256;
    const size_t colBase = (size_t)bx * 128;

    const int srow   = lane >> 2;
    const int schunk = ((lane & 3) ^ ((lane >> 3) & 3)) << 3;
    const bf16* aG0 = A + (rowBase + 16 * wave       + srow) * (size_t)D_MODEL + schunk;
    const bf16* aG1 = A + (rowBase + 128 + 16 * wave + srow) * (size_t)D_MODEL + schunk;
    const bf16* bG  = W + (colBase + 16 * wave       + srow) * (size_t)D_MODEL + schunk;

#define STAGEW(tt, sAp, sBp) do {                                               \
        const size_t ko_ = (size_t)(tt) * 32;                                   \
        gld_lds16(aG0 + ko_, (sAp) + 512 * wave);                               \
        gld_lds16(aG1 + ko_, (sAp) + 512 * (8 + wave));                         \
        gld_lds16(bG  + ko_, (sBp) + 512 * wave);                               \
    } while (0)

    f32x4 accv[4][4];
    #pragma unroll
    for (int i = 0; i < 4; ++i)
        #pragma unroll
        for (int j = 0; j < 4; ++j)
            accv[i][j] = f32x4{0.f, 0.f, 0.f, 0.f};

    const int l15 = lane & 15;
    const int cs = (((lane >> 4) ^ ((l15 >> 1) & 3)) << 3);
    const int arow0 = wr * 64 + l15;
    const int brow0 = wc * 64 + l15;

    STAGEW(0, &ldsA[0][0], &ldsB[0][0]);
    STAGEW(1, &ldsA[1][0], &ldsB[1][0]);

    int rs = 0, ps = 2;
    #pragma unroll 1
    for (int t = 0; t < 32; ++t) {
        if (t < 31) { asm volatile("s_waitcnt vmcnt(3)" ::: "memory"); }
        else        { asm volatile("s_waitcnt vmcnt(0)" ::: "memory"); }
        __builtin_amdgcn_s_barrier();
        __builtin_amdgcn_sched_barrier(0);

        if (t + 2 < 32) STAGEW(t + 2, &ldsA[ps][0], &ldsB[ps][0]);

        const bf16* Ab = &ldsA[rs][0];
        const bf16* Bb = &ldsB[rs][0];
        bf16x8 af[4], bv[4];
        #pragma unroll
        for (int i = 0; i < 4; ++i)
            af[i] = *(const bf16x8*)(Ab + (arow0 + 16 * i) * 32 + cs);
        #pragma unroll
        for (int j = 0; j < 4; ++j)
            bv[j] = *(const bf16x8*)(Bb + (brow0 + 16 * j) * 32 + cs);
        #pragma unroll
        for (int i = 0; i < 4; ++i)
            #pragma unroll
            for (int j = 0; j < 4; ++j)
                accv[i][j] = __builtin_amdgcn_mfma_f32_16x16x32_bf16(
                    af[i], bv[j], accv[i][j], 0, 0, 0);

        rs = (rs == 2) ? 0 : rs + 1;
        ps = (ps == 2) ? 0 : ps + 1;
    }
#undef STAGEW

    const int cl = l15;
    const int rg = (lane >> 4) * 4;
    #pragma unroll
    for (int i = 0; i < 4; ++i) {
        #pragma unroll
        for (int j = 0; j < 4; ++j) {
            int col = (int)colBase + wc * 64 + j * 16 + cl;
            size_t base = (rowBase + wr * 64 + i * 16 + rg) * (size_t)ldc + col;
            if (bfout) {
                bf16* Cb = (bf16*)C;
                #pragma unroll
                for (int r = 0; r < 4; ++r)
                    Cb[base + (size_t)r * ldc] = __float2bfloat16(accv[i][j][r]);
            } else {
                #pragma unroll
                for (int r = 0; r < 4; ++r)
                    C[base + (size_t)r * ldc] = accv[i][j][r];
            }
        }
    }
}

// ---------------- causal depthwise conv (k=4) + bias + silu, 2 d x 8 l per thread ----
__global__ __launch_bounds__(256) void conv_silu_kernel(const bf16* __restrict__ xz,
                                                        const float* __restrict__ cw,
                                                        const float* __restrict__ cb,
                                                        bf16* __restrict__ xcb) {
    int d  = (blockIdx.x * 256 + threadIdx.x) * 2;
    int l0 = blockIdx.y * 8;
    int b  = blockIdx.z;
    float4 wa = *(const float4*)(cw + d * 4);
    float4 wb = *(const float4*)(cw + d * 4 + 4);
    float2 bias = *(const float2*)(cb + d);
    const bf16* base = xz + (size_t)b * SEQLEN * (2 * D_INNER) + d;

    float a0 = 0.f, a1 = 0.f, a2 = 0.f;
    float b0 = 0.f, b1 = 0.f, b2 = 0.f;
    #pragma unroll
    for (int j = 0; j < 3; ++j) {
        int l = l0 - 3 + j;
        float va = 0.f, vb = 0.f;
        if (l >= 0) {
            unsigned v;
            __builtin_memcpy(&v, base + (size_t)l * (2 * D_INNER), 4);
            va = bfu((unsigned short)v);
            vb = bfu((unsigned short)(v >> 16));
        }
        if (j == 0) { a0 = va; b0 = vb; }
        else if (j == 1) { a1 = va; b1 = vb; }
        else { a2 = va; b2 = vb; }
    }
    #pragma unroll
    for (int i = 0; i < 8; ++i) {
        unsigned v;
        __builtin_memcpy(&v, base + (size_t)(l0 + i) * (2 * D_INNER), 4);
        float ca = bfu((unsigned short)v);
        float cbv = bfu((unsigned short)(v >> 16));
        float sa = silu_fast(bias.x + wa.x * a0 + wa.y * a1 + wa.z * a2 + wa.w * ca);
        float sb = silu_fast(bias.y + wb.x * b0 + wb.y * b1 + wb.z * b2 + wb.w * cbv);
        unsigned o = (unsigned)bfb(sa) | ((unsigned)bfb(sb) << 16);
        unsigned* dst = (unsigned*)(xcb + ((size_t)b * SEQLEN + l0 + i) * D_INNER + d);
        *dst = o;
        a0 = a1; a1 = a2; a2 = ca;
        b0 = b1; b1 = b2; b2 = cbv;
    }
}

// ---------------- x_proj split-K reduce: sum 16 bf16 partials -> bf16 ----------------
__global__ __launch_bounds__(256) void reduce_xproj(const bf16* __restrict__ px,
                                                    bf16* __restrict__ dbl_b) {
    int i = blockIdx.x * 256 + threadIdx.x;
    float s = 0.f;
    #pragma unroll
    for (int z = 0; z < XPZ; ++z) {
        unsigned short v;
        __builtin_memcpy(&v, px + (size_t)z * (TOKENS * 96) + i, 2);
        s += bfu(v);
    }
    dbl_b[i] = __float2bfloat16(s);
}

// ---------------- out_proj reduce (bf16 partials) + residual + rmsnorm -> u_b ----
__global__ __launch_bounds__(256) void reduce_oproj_rms(const bf16* __restrict__ po,
                                                        float* __restrict__ h,
                                                        const float* __restrict__ w,
                                                        bf16* __restrict__ u) {
    int t = blockIdx.x;
    size_t base = (size_t)t * D_MODEL + threadIdx.x * 4;
    ushort4 ua = *(const ushort4*)(po + base);
    ushort4 ub = *(const ushort4*)(po + (size_t)TOKENS * D_MODEL + base);
    float4 hv = *(const float4*)(h + base);
    hv.x += bfu(ua.x) + bfu(ub.x);
    hv.y += bfu(ua.y) + bfu(ub.y);
    hv.z += bfu(ua.z) + bfu(ub.z);
    hv.w += bfu(ua.w) + bfu(ub.w);
    *(float4*)(h + base) = hv;
    float ss = hv.x*hv.x + hv.y*hv.y + hv.z*hv.z + hv.w*hv.w;
    #pragma unroll
    for (int off = 32; off > 0; off >>= 1) ss += __shfl_down(ss, off);
    __shared__ float red[4];
    int lane = threadIdx.x & 63, wid = threadIdx.x >> 6;
    if (lane == 0) red[wid] = ss;
    __syncthreads();
    float tot = red[0] + red[1] + red[2] + red[3];
    float scale = rsqrtf(tot * (1.0f / (float)D_MODEL) + 1e-5f);
    float4 wq = ((const float4*)w)[threadIdx.x];
    u[base+0] = __float2bfloat16(hv.x * scale * wq.x);
    u[base+1] = __float2bfloat16(hv.y * scale * wq.y);
    u[base+2] = __float2bfloat16(hv.z * scale * wq.z);
    u[base+3] = __float2bfloat16(hv.w * scale * wq.w);
}

// ---------------- scan phase A: per-chunk summaries (zero init) ----------------
__global__ __launch_bounds__(256) void scan_chunk(const bf16* __restrict__ dtp,
                                                  const float* __restrict__ dt_bias,
                                                  const bf16* __restrict__ dbl,
                                                  const bf16* __restrict__ xc,
                                                  const float* __restrict__ A_log,
                                                  float* __restrict__ dts_out,
                                                  bf16* __restrict__ sfin) {
    int d = blockIdx.x * 256 + threadIdx.x;
    int c = blockIdx.y;
    int b = blockIdx.z;
    __shared__ float Bs[CL][D_STATE];
    {
        int i = threadIdx.x;
        int l = i >> 4, n = i & 15;
        Bs[l][n] = __bfloat162float(dbl[((size_t)b * SEQLEN + c * CL + l) * 96 + DT_RANK + n]);
    }
    __syncthreads();
    float A[D_STATE];
    #pragma unroll
    for (int n = 0; n < D_STATE; ++n) A[n] = -__expf(A_log[d * D_STATE + n]);
    float bias = dt_bias[d];
    float st[D_STATE];
    #pragma unroll
    for (int n = 0; n < D_STATE; ++n) st[n] = 0.f;
    float dts = 0.f;
    for (int l = 0; l < CL; ++l) {
        size_t t = (size_t)b * SEQLEN + c * CL + l;
        float dtv = softplus_fast(__bfloat162float(dtp[t * D_INNER + d]) + bias);
        dts += dtv;
        float dx = dtv * __bfloat162float(xc[t * D_INNER + d]);
        #pragma unroll
        for (int n = 0; n < D_STATE; ++n) {
            float a = __expf(dtv * A[n]);
            st[n] = a * st[n] + dx * Bs[l][n];
        }
    }
    dts_out[((size_t)b * NC + c) * D_INNER + d] = dts;
    #pragma unroll
    for (int n = 0; n < D_STATE; ++n) {
        size_t o = (((size_t)b * NC + c) * D_STATE + n) * D_INNER + d;
        sfin[o] = __float2bfloat16(st[n]);
    }
}

// ---------------- scan phase B: carry chunk-initial states (f32 accum) ----------
__global__ __launch_bounds__(256) void scan_carry(const float* __restrict__ dts,
                                                  const bf16* __restrict__ sfin,
                                                  const float* __restrict__ A_log,
                                                  bf16* __restrict__ initS) {
    int idx = blockIdx.x * 256 + threadIdx.x;
    int d = idx & (D_INNER - 1);
    int n = (idx >> 11) & (D_STATE - 1);
    int b = idx >> 15;
    float A = -__expf(A_log[d * D_STATE + n]);
    float st = 0.f;
    for (int c = 0; c < NC; ++c) {
        size_t o = (((size_t)b * NC + c) * D_STATE + n) * D_INNER + d;
        initS[o] = __float2bfloat16(st);
        float ap = __expf(dts[((size_t)b * NC + c) * D_INNER + d] * A);
        st = ap * st + __bfloat162float(sfin[o]);
    }
}

// ---------------- scan phase C: recompute with true init, emit gated y ----------------
__global__ __launch_bounds__(256) void scan_emit(const bf16* __restrict__ dtp,
                                                 const float* __restrict__ dt_bias,
                                                 const bf16* __restrict__ dbl,
                                                 const bf16* __restrict__ xc,
                                                 const bf16* __restrict__ xz,
                                                 const float* __restrict__ A_log,
                                                 const float* __restrict__ Dp,
                                                 const bf16* __restrict__ initS,
                                                 bf16* __restrict__ y) {
    int d = blockIdx.x * 256 + threadIdx.x;
    int c = blockIdx.y;
    int b = blockIdx.z;
    __shared__ float BCs[CL][2 * D_STATE];
    for (int i = threadIdx.x; i < CL * 2 * D_STATE; i += 256) {
        int l = i >> 5, n = i & 31;
        BCs[l][n] = __bfloat162float(dbl[((size_t)b * SEQLEN + c * CL + l) * 96 + DT_RANK + n]);
    }
    __syncthreads();
    float A[D_STATE];
    #pragma unroll
    for (int n = 0; n < D_STATE; ++n) A[n] = -__expf(A_log[d * D_STATE + n]);
    float bias = dt_bias[d];
    float Dv = Dp[d];
    float st[D_STATE];
    #pragma unroll
    for (int n = 0; n < D_STATE; ++n)
        st[n] = __bfloat162float(initS[(((size_t)b * NC + c) * D_STATE + n) * D_INNER + d]);
    for (int l = 0; l < CL; ++l) {
        size_t t = (size_t)b * SEQLEN + c * CL + l;
        float dtv = softplus_fast(__bfloat162float(dtp[t * D_INNER + d]) + bias);
        float xcv = __bfloat162float(xc[t * D_INNER + d]);
        float dx = dtv * xcv;
        float acc = 0.f;
        #pragma unroll
        for (int n = 0; n < D_STATE; ++n) {
            float a = __expf(dtv * A[n]);
            st[n] = a * st[n] + dx * BCs[l][n];
            acc += st[n] * BCs[l][D_STATE + n];
        }
        acc += xcv * Dv;
        float zv = __bfloat162float(xz[t * (2 * D_INNER) + D_INNER + d]);
        y[t * D_INNER + d] = __float2bfloat16(acc * silu_fast(zv));
    }
}

extern "C" void kernel_launch(void* const* d_in, const int* in_sizes, int n_in,
                              void* d_out, int out_size, void* d_ws, size_t ws_size,
                              hipStream_t stream) {
    const int*   x          = (const int*)  d_in[0];
    const float* emb        = (const float*)d_in[1];
    const float* norm_w     = (const float*)d_in[2];
    const float* in_proj_w  = (const float*)d_in[3];
    const float* conv_w     = (const float*)d_in[4];
    const float* conv_b     = (const float*)d_in[5];
    const float* x_proj_w   = (const float*)d_in[6];
    const float* dt_proj_w  = (const float*)d_in[7];
    const float* dt_bias    = (const float*)d_in[8];
    const float* A_log      = (const float*)d_in[9];
    const float* Dp         = (const float*)d_in[10];
    const float* out_proj_w = (const float*)d_in[11];
    const float* fnorm_w    = (const float*)d_in[12];
    float* out = (float*)d_out;
    float* ws  = (float*)d_ws;

    // ---- ws scratch layout (float offsets) ----
    bf16*  embf   = (bf16*)ws;              // [32000][1024] bf16
    bf16*  u_b    = (bf16*)(ws + 16384000); // [2048][1024] bf16
    bf16*  xz_b   = (bf16*)(ws + 17432576); // [2048][4096] bf16
    bf16*  dtp_b  = (bf16*)(ws + 25821184); // [2048][2048] bf16
    bf16*  xc_b   = (bf16*)(ws + 30015488); // [2048][2048] bf16
    float* h      = ws + 36306944;          // [2048][1024]
    bf16*  dbl_b  = (bf16*)(ws + 38600704); // [2048][96] bf16
    bf16*  y_b    = (bf16*)(ws + 38699008); // [2048][2048] bf16
    bf16*  inpj_b = (bf16*)(ws + 40796160); // [2][4096][1024] bf16
    bf16*  xpj_b  = (bf16*)(ws + 44990464); // [2][128][2048] bf16
    bf16*  dtpj_b = (bf16*)(ws + 45252608); // [2][2048][64] bf16
    bf16*  otpj_b = (bf16*)(ws + 45383680); // [2][1024][2048] bf16
    float* dts    = ws + 47480832;          // [2][64][2048] f32
    bf16*  sfin   = (bf16*)(ws + 49577984); // [2][64][16][2048] bf16
    bf16*  initS  = (bf16*)(ws + 51675136); // [2][64][16][2048] bf16
    bf16*  px_b   = (bf16*)(ws + 53772288); // [16][2048][96] bf16
    bf16*  po_b   = (bf16*)(ws + 56918016); // [2][2048][1024] bf16

    f32_to_bf16<<<(VOCAB*D_MODEL/4 + 255)/256, 256, 0, stream>>>(emb, embf, VOCAB*D_MODEL);
    f32_to_bf16<<<(2*2*D_INNER*D_MODEL/4 + 255)/256, 256, 0, stream>>>(in_proj_w,  inpj_b, 2*2*D_INNER*D_MODEL);
    conv_xproj_pad<<<dim3(D_INNER/256, 128, N_LAYER), 256, 0, stream>>>(x_proj_w, xpj_b);
    f32_to_bf16<<<(2*D_INNER*DT_RANK/4 + 255)/256, 256, 0, stream>>>(dt_proj_w,  dtpj_b, 2*D_INNER*DT_RANK);
    f32_to_bf16<<<(2*D_MODEL*D_INNER/4 + 255)/256, 256, 0, stream>>>(out_proj_w, otpj_b, 2*D_MODEL*D_INNER);

    embed_rms<<<TOKENS, 256, 0, stream>>>(x, emb, norm_w, h, u_b);

    for (int layer = 0; layer < N_LAYER; ++layer) {
        gemm_wide3<<<dim3(4096/128, TOKENS/256), 512, 0, stream>>>(
            u_b, inpj_b + (size_t)layer * 2 * D_INNER * D_MODEL,
            (float*)xz_b, 2 * D_INNER, 1);
        conv_silu_kernel<<<dim3(D_INNER/512, SEQLEN/8, BATCH), 256, 0, stream>>>(
            xz_b, conv_w + (size_t)layer * D_INNER * D_CONV, conv_b + layer * D_INNER,
            xc_b);
        gemm_bf16<<<dim3(1, TOKENS/128, XPZ), 256, 0, stream>>>(
            xc_b, D_INNER, xpj_b + (size_t)layer * 128 * D_INNER, D_INNER,
            (float*)px_b, 96, 96, 128, 0, 0, TOKENS, 1);
        reduce_xproj<<<(TOKENS*96)/256, 256, 0, stream>>>(px_b, dbl_b);
        gemm_bf16<<<dim3(D_INNER/128, TOKENS/128), 256, 0, stream>>>(
            dbl_b, 96, dtpj_b + (size_t)layer * D_INNER * DT_RANK, DT_RANK,
            (float*)dtp_b, D_INNER, D_INNER, DT_RANK, 0, 1, TOKENS, 1);
        scan_chunk<<<dim3(D_INNER/256, NC, BATCH), 256, 0, stream>>>(
            dtp_b, dt_bias + layer * D_INNER, dbl_b, xc_b,
            A_log + (size_t)layer * D_INNER * D_STATE, dts, sfin);
        scan_carry<<<(BATCH*D_STATE*D_INNER)/256, 256, 0, stream>>>(
            dts, sfin, A_log + (size_t)layer * D_INNER * D_STATE, initS);
        scan_emit<<<dim3(D_INNER/256, NC, BATCH), 256, 0, stream>>>(
            dtp_b, dt_bias + layer * D_INNER, dbl_b, xc_b, xz_b,
            A_log + (size_t)layer * D_INNER * D_STATE, Dp + layer * D_INNER,
            initS, y_b);
        gemm_bf16<<<dim3(D_MODEL/128, TOKENS/128, 2), 256, 0, stream>>>(
            y_b, D_INNER, otpj_b + (size_t)layer * D_MODEL * D_INNER, D_INNER,
            (float*)po_b, D_MODEL, D_MODEL, 1024, 0, 1, TOKENS, 1);
        reduce_oproj_rms<<<TOKENS, 256, 0, stream>>>(
            po_b, h, (layer + 1 < N_LAYER) ? (norm_w + (layer + 1) * D_MODEL) : fnorm_w,
            u_b);
    }

    // vocab GEMM: proven 8-wave 3-slot kernel, 250x8 grid, f32 out
    gemm_wide3<<<dim3(VOCAB/128, TOKENS/256), 512, 0, stream>>>(u_b, embf, out, VOCAB, 0);
}